// Round 1
// baseline (173.529 us; speedup 1.0000x reference)
//
#include <hip/hip_runtime.h>
#include <cstdint>
#include <cstddef>

// RoGPE node encoder: MLP -> angles a0[N]; then 3-hop aggregation where
// hop1 = raw edge scatter (dupes kept), hops 2,3 = boolean adjacency powers
// (unique paths) as bitset row-ORs + masked dot products.
//
// s1 = ln2 * scatter(a0[col] -> row);          a1 = a0 + s1
// A2 = (A@A)>0;  s2 = s1 + ln3*(A2@a1);        a2 = a1 + s2
// A3 = (A2@A)>0; s3 = s2 + ln4*(A3@a2);        out = a2 + s3

constexpr int NN  = 4096;   // nodes
constexpr int D   = 128;    // feature dim
constexpr int NE  = 131072; // edges
constexpr int WPR = 64;     // u64 words per bitset row (4096 bits)

__device__ __forceinline__ float wave_sum64(float v) {
#pragma unroll
  for (int off = 32; off >= 1; off >>= 1) v += __shfl_xor(v, off, 64);
  return v;
}

// ---------------- MLP ----------------
// Y[n,o] = relu(sum_i X[n,i]*W[o,i] (+ b[o]))   (torch Linear, W=[out,in])
// W staged in LDS with +i swizzle: Wl[i*128 + ((i+o)&127)] = W[o*128+i]
//  -> global load coalesced, LDS write conflict-free, LDS read 2-way (free).
// Each wave: 2 nodes x 2 outputs/lane. FINAL variant fuses the W3 dot -> a0[n].
template <bool HAS_BIAS, bool FINAL>
__global__ __launch_bounds__(256) void mlp_kernel(
    const float* __restrict__ X, const float* __restrict__ W,
    const float* __restrict__ bias, const float* __restrict__ W3,
    const float* __restrict__ b3, float* __restrict__ Y) {
  __shared__ float Wl[D * D];
  __shared__ float Xl[8 * D];
  const int t = threadIdx.x;
#pragma unroll 8
  for (int j = 0; j < 64; ++j) {
    int idx = t + j * 256;
    int o = idx >> 7, i = idx & 127;
    Wl[i * D + ((i + o) & 127)] = W[idx];
  }
  const int node0 = blockIdx.x * 8;
#pragma unroll
  for (int j = 0; j < 4; ++j) {
    int idx = t + j * 256;
    Xl[idx] = X[node0 * D + idx];
  }
  __syncthreads();
  const int wave = t >> 6, lane = t & 63;
  const int nA = wave * 2, nB = nA + 1;
  const float* xA = &Xl[nA * D];
  const float* xB = &Xl[nB * D];
  float accA0 = 0.f, accA1 = 0.f, accB0 = 0.f, accB1 = 0.f;
#pragma unroll 8
  for (int i = 0; i < D; ++i) {
    float w0 = Wl[i * D + ((i + lane) & 127)];
    float w1 = Wl[i * D + ((i + lane + 64) & 127)];
    float xa = xA[i], xb = xB[i];
    accA0 = fmaf(xa, w0, accA0);
    accA1 = fmaf(xa, w1, accA1);
    accB0 = fmaf(xb, w0, accB0);
    accB1 = fmaf(xb, w1, accB1);
  }
  if (HAS_BIAS) {
    float bl = bias[lane], bh = bias[lane + 64];
    accA0 += bl; accA1 += bh; accB0 += bl; accB1 += bh;
  }
  accA0 = fmaxf(accA0, 0.f); accA1 = fmaxf(accA1, 0.f);
  accB0 = fmaxf(accB0, 0.f); accB1 = fmaxf(accB1, 0.f);
  if (!FINAL) {
    float* y = Y + (size_t)(node0 + nA) * D;
    y[lane] = accA0;
    y[lane + 64] = accA1;
    y += D;
    y[lane] = accB0;
    y[lane + 64] = accB1;
  } else {
    float w3l = W3[lane], w3h = W3[lane + 64];
    float pA = fmaf(accA0, w3l, accA1 * w3h);
    float pB = fmaf(accB0, w3l, accB1 * w3h);
    pA = wave_sum64(pA);
    pB = wave_sum64(pB);
    if (lane == 0) {
      float bb = b3[0];
      Y[node0 + nA] = pA + bb;
      Y[node0 + nB] = pB + bb;
    }
  }
}

// ---------------- graph build: bitset adjacency + hop-1 scatter ----------------
__global__ __launch_bounds__(256) void build_graph(
    const int* __restrict__ er, const int* __restrict__ ec,
    const float* __restrict__ a0, unsigned long long* __restrict__ A,
    float* __restrict__ s1) {
  int e = blockIdx.x * 256 + threadIdx.x;
  if (e >= NE) return;
  int r = er[e] & (NN - 1);
  int c = ec[e] & (NN - 1);
  atomicOr(&A[(size_t)r * WPR + (c >> 6)], 1ull << (c & 63));
  atomicAdd(&s1[r], a0[c] * 0.6931471805599453f);  // ln 2
}

// a1 = a0 + s1; ws1[w] = sum_{b<64} a1[w*64+b]  (single block)
__global__ void a1_ws(const float* __restrict__ a0, const float* __restrict__ s1,
                      float* __restrict__ a1, float* __restrict__ ws1) {
  int t = threadIdx.x;
  for (int j = t; j < NN; j += 256) a1[j] = a0[j] + s1[j];
  __syncthreads();
  if (t < WPR) {
    float s = 0.f;
    const float* p = a1 + t * 64;
#pragma unroll 8
    for (int b = 0; b < 64; ++b) s += p[b];
    ws1[t] = s;
  }
}

// One wave per row i. lane = word index.
// acc = OR_{k in N1(i)} SRC[k]  (SRC=A -> A2 row; SRC=A2 -> A3 row)
// Then masked dot with vector v using per-word partial sums (complement trick
// when a word is >50% dense), wave-reduce, epilogue.
__device__ __forceinline__ unsigned long long gather_row(
    const unsigned long long* __restrict__ Arow_src,   // bitset giving neighbor set (row i of A)
    const unsigned long long* __restrict__ SRC,        // rows to OR
    int i, int lane) {
  unsigned long long rw = Arow_src[(size_t)i * WPR + lane];
  unsigned long long acc = 0ull;
#pragma unroll 4
  for (int w = 0; w < WPR; ++w) {
    unsigned long long bits = __shfl(rw, w, 64);  // word w of row i (uniform)
    int kbase = w << 6;
    while (bits) {
      int b = __builtin_ctzll(bits);
      bits &= bits - 1ull;
      acc |= SRC[(size_t)(kbase + b) * WPR + lane];  // coalesced 512B row read
    }
  }
  return acc;
}

__device__ __forceinline__ float masked_dot(
    unsigned long long m, const float* __restrict__ v,
    const float* __restrict__ wsum, int lane) {
  int cnt = __popcll(m);
  bool inv = cnt > 32;
  unsigned long long it = inv ? ~m : m;
  float part = inv ? wsum[lane] : 0.f;
  float sgn = inv ? -1.f : 1.f;
  const float* p = v + (lane << 6);
  while (it) {
    int b = __builtin_ctzll(it);
    it &= it - 1ull;
    part += sgn * p[b];
  }
  return part;
}

__global__ __launch_bounds__(256) void hop2_kernel(
    const unsigned long long* __restrict__ A, unsigned long long* __restrict__ A2,
    const float* __restrict__ a1, const float* __restrict__ ws1,
    const float* __restrict__ s1, float* __restrict__ s2, float* __restrict__ a2) {
  int gid = blockIdx.x * 256 + threadIdx.x;
  int i = gid >> 6, lane = gid & 63;
  if (i >= NN) return;
  unsigned long long acc = gather_row(A, A, i, lane);
  A2[(size_t)i * WPR + lane] = acc;
  float part = masked_dot(acc, a1, ws1, lane);
  part = wave_sum64(part);
  if (lane == 0) {
    float s2v = fmaf(1.0986122886681098f, part, s1[i]);  // + ln3 * t2
    s2[i] = s2v;
    a2[i] = a1[i] + s2v;
  }
}

__global__ void ws2_kernel(const float* __restrict__ a2, float* __restrict__ ws2) {
  int t = threadIdx.x;
  if (t < WPR) {
    float s = 0.f;
    const float* p = a2 + t * 64;
#pragma unroll 8
    for (int b = 0; b < 64; ++b) s += p[b];
    ws2[t] = s;
  }
}

__global__ __launch_bounds__(256) void hop3_kernel(
    const unsigned long long* __restrict__ A, const unsigned long long* __restrict__ A2,
    const float* __restrict__ a2, const float* __restrict__ ws2,
    const float* __restrict__ s2, float* __restrict__ out) {
  int gid = blockIdx.x * 256 + threadIdx.x;
  int i = gid >> 6, lane = gid & 63;
  if (i >= NN) return;
  unsigned long long acc = gather_row(A, A2, i, lane);  // A3 row, never stored
  float part = masked_dot(acc, a2, ws2, lane);
  part = wave_sum64(part);
  if (lane == 0) {
    // out = a2 + s3,  s3 = s2 + ln4 * t3
    out[i] = a2[i] + fmaf(1.3862943611198906f, part, s2[i]);
  }
}

extern "C" void kernel_launch(void* const* d_in, const int* in_sizes, int n_in,
                              void* d_out, int out_size, void* d_ws, size_t ws_size,
                              hipStream_t stream) {
  const float* coeffs = (const float*)d_in[0];
  const int*   edge   = (const int*)d_in[1];   // [2, NE] int32
  const float* W0 = (const float*)d_in[2];
  const float* b0 = (const float*)d_in[3];
  const float* W1 = (const float*)d_in[4];
  const float* W2 = (const float*)d_in[5];
  const float* W3 = (const float*)d_in[6];
  const float* b3 = (const float*)d_in[7];
  float* out = (float*)d_out;

  char* ws = (char*)d_ws;
  // h1/h2 alias A/A2: h1 dead after layer-1 kernel, h2 dead after mlp_final;
  // A is memset AFTER mlp chain, A2 first written in hop2. Stream order makes
  // the aliasing safe. Total footprint: 4 MB + ~81 KB.
  float* h1 = (float*)ws;                                   // 2 MB
  float* h2 = (float*)(ws + (2u << 20));                    // 2 MB
  unsigned long long* A  = (unsigned long long*)ws;         // 2 MB (aliases h1)
  unsigned long long* A2 = (unsigned long long*)(ws + (2u << 20)); // (aliases h2)
  float* vec = (float*)(ws + (4u << 20));
  float* a0v = vec;              // 4096
  float* s1  = vec + 4096;
  float* a1v = vec + 8192;
  float* s2  = vec + 12288;
  float* a2v = vec + 16384;
  float* ws1 = vec + 20480;      // 64
  float* ws2 = vec + 20544;      // 64

  // ---- MLP: coeffs -> h1 -> h2 -> a0 ----
  mlp_kernel<true,  false><<<NN / 8, 256, 0, stream>>>(coeffs, W0, b0, nullptr, nullptr, h1);
  mlp_kernel<false, false><<<NN / 8, 256, 0, stream>>>(h1, W1, nullptr, nullptr, nullptr, h2);
  mlp_kernel<false, true ><<<NN / 8, 256, 0, stream>>>(h2, W2, nullptr, W3, b3, a0v);

  // ---- zero adjacency + hop-1 accumulator (ws is poisoned 0xAA each call) ----
  hipMemsetAsync(A, 0, (size_t)NN * WPR * sizeof(unsigned long long), stream);
  hipMemsetAsync(s1, 0, (size_t)NN * sizeof(float), stream);

  build_graph<<<NE / 256, 256, 0, stream>>>(edge, edge + NE, a0v, A, s1);
  a1_ws<<<1, 256, 0, stream>>>(a0v, s1, a1v, ws1);
  hop2_kernel<<<NN / 4, 256, 0, stream>>>(A, A2, a1v, ws1, s1, s2, a2v);
  ws2_kernel<<<1, 64, 0, stream>>>(a2v, ws2);
  hop3_kernel<<<NN / 4, 256, 0, stream>>>(A, A2, a2v, ws2, s2, out);
}

// Round 2
// 165.580 us; speedup vs baseline: 1.0480x; 1.0480x over previous
//
#include <hip/hip_runtime.h>
#include <cstdint>
#include <cstddef>

// RoGPE node encoder: MLP -> angles a0[N]; then 3-hop aggregation where
// hop1 = raw edge scatter (dupes kept), hops 2,3 = boolean adjacency powers
// (unique paths) as bitset row-ORs + masked dot products.
//
// s1 = ln2 * scatter(a0[col] -> row);          a1 = a0 + s1
// A2 = (A@A)>0;  s2 = s1 + ln3*(A2@a1);        a2 = a1 + s2
// A3 = (A2@A)>0; s3 = s2 + ln4*(A3@a2);        out = a2 + s3
//
// R1 -> R2: fused 3-layer MLP (one kernel, one LDS W buffer recycled, no
// h1/h2 global round-trip), single memset region (A|s1|ws2), ws2 folded into
// hop2 epilogue via atomicAdd, gather via LDS neighbor list + 4-wide
// pipelined loads. Graph nodes: 9 -> 6.

constexpr int NN  = 4096;   // nodes
constexpr int D   = 128;    // feature dim
constexpr int NE  = 131072; // edges
constexpr int WPR = 64;     // u64 words per bitset row (4096 bits)
constexpr int MAXN = 256;   // neighbor-list cap (row degree ~Binom(131072,1/4096), mean 32, max~60)

__device__ __forceinline__ float wave_sum64(float v) {
#pragma unroll
  for (int off = 32; off >= 1; off >>= 1) v += __shfl_xor(v, off, 64);
  return v;
}

// ---------------- fused MLP ----------------
// All 4 layers per node in one kernel (rows independent). Per block: 8 nodes.
// W staged in LDS with +i swizzle: Wl[i*128 + ((i+o)&127)] = W[o*128+i]
//  -> global load coalesced, LDS write conflict-free, LDS read 2-way (free).
// Hidden activations ping-pong between two 4KB LDS X buffers.
// Each wave: 2 nodes x 2 outputs/lane; final W3 dot fused -> a0[n].
__global__ __launch_bounds__(256) void mlp_all(
    const float* __restrict__ X,
    const float* __restrict__ W0, const float* __restrict__ b0,
    const float* __restrict__ W1, const float* __restrict__ W2,
    const float* __restrict__ W3, const float* __restrict__ b3,
    float* __restrict__ a0) {
  __shared__ float Wl[D * D];
  __shared__ float Xa[8 * D];
  __shared__ float Xb[8 * D];
  const int t = threadIdx.x;
  const int node0 = blockIdx.x * 8;
#pragma unroll
  for (int j = 0; j < 4; ++j) {
    int idx = t + j * 256;
    Xa[idx] = X[node0 * D + idx];
  }
  const int wave = t >> 6, lane = t & 63;
  const float* Wsrc[3] = {W0, W1, W2};
  float* Xcur = Xa;
  float* Xnxt = Xb;
  float accA0 = 0.f, accA1 = 0.f, accB0 = 0.f, accB1 = 0.f;
#pragma unroll
  for (int L = 0; L < 3; ++L) {
    __syncthreads();  // prev compute done with Wl; (L=0: Xa writes visible)
    const float* W = Wsrc[L];
#pragma unroll 8
    for (int j = 0; j < 64; ++j) {
      int idx = t + j * 256;
      int o = idx >> 7, i = idx & 127;
      Wl[i * D + ((i + o) & 127)] = W[idx];
    }
    __syncthreads();
    const float* xA = &Xcur[(wave * 2) * D];
    const float* xB = xA + D;
    accA0 = accA1 = accB0 = accB1 = 0.f;
#pragma unroll 8
    for (int i = 0; i < D; ++i) {
      float w0 = Wl[i * D + ((i + lane) & 127)];
      float w1 = Wl[i * D + ((i + lane + 64) & 127)];
      float xa = xA[i], xb = xB[i];
      accA0 = fmaf(xa, w0, accA0);
      accA1 = fmaf(xa, w1, accA1);
      accB0 = fmaf(xb, w0, accB0);
      accB1 = fmaf(xb, w1, accB1);
    }
    if (L == 0) {
      float bl = b0[lane], bh = b0[lane + 64];
      accA0 += bl; accA1 += bh; accB0 += bl; accB1 += bh;
    }
    accA0 = fmaxf(accA0, 0.f); accA1 = fmaxf(accA1, 0.f);
    accB0 = fmaxf(accB0, 0.f); accB1 = fmaxf(accB1, 0.f);
    if (L < 2) {
      float* y = &Xnxt[(wave * 2) * D];
      y[lane] = accA0;
      y[lane + 64] = accA1;
      y[D + lane] = accB0;
      y[D + lane + 64] = accB1;
      float* tmp = Xcur; Xcur = Xnxt; Xnxt = tmp;
    }
  }
  // final 128->1 dot
  float w3l = W3[lane], w3h = W3[lane + 64];
  float pA = fmaf(accA0, w3l, accA1 * w3h);
  float pB = fmaf(accB0, w3l, accB1 * w3h);
  pA = wave_sum64(pA);
  pB = wave_sum64(pB);
  if (lane == 0) {
    float bb = b3[0];
    a0[node0 + wave * 2] = pA + bb;
    a0[node0 + wave * 2 + 1] = pB + bb;
  }
}

// ---------------- graph build: bitset adjacency + hop-1 scatter ----------------
__global__ __launch_bounds__(256) void build_graph(
    const int* __restrict__ er, const int* __restrict__ ec,
    const float* __restrict__ a0, unsigned long long* __restrict__ A,
    float* __restrict__ s1) {
  int e = blockIdx.x * 256 + threadIdx.x;
  if (e >= NE) return;
  int r = er[e] & (NN - 1);
  int c = ec[e] & (NN - 1);
  atomicOr(&A[(size_t)r * WPR + (c >> 6)], 1ull << (c & 63));
  atomicAdd(&s1[r], a0[c] * 0.6931471805599453f);  // ln 2
}

// a1 = a0 + s1; ws1[w] = sum_{b<64} a1[w*64+b]  (single block)
__global__ void a1_ws(const float* __restrict__ a0, const float* __restrict__ s1,
                      float* __restrict__ a1, float* __restrict__ ws1) {
  int t = threadIdx.x;
  for (int j = t; j < NN; j += 256) a1[j] = a0[j] + s1[j];
  __syncthreads();
  if (t < WPR) {
    float s = 0.f;
    const float* p = a1 + t * 64;
#pragma unroll 8
    for (int b = 0; b < 64; ++b) s += p[b];
    ws1[t] = s;
  }
}

// One wave per row i, lane = word index of the output bitset row.
// Phase 1: wave compacts row i's neighbor indices into an LDS list
// (wave-synchronous, LDS atomic counter). Phase 2: 4-wide unrolled OR-gather
// so 4 independent 512B row loads are in flight per vmcnt batch.
__device__ __forceinline__ unsigned long long gather_row_fast(
    const unsigned long long* __restrict__ A,
    const unsigned long long* __restrict__ SRC,
    int i, int lane, unsigned short* __restrict__ nbr, int* __restrict__ ncnt) {
  if (lane == 0) *ncnt = 0;
  unsigned long long rw = A[(size_t)i * WPR + lane];
  int c = __popcll(rw);
  int base = 0;
  if (c) base = atomicAdd(ncnt, c);
  while (rw) {
    int b = __builtin_ctzll(rw);
    rw &= rw - 1ull;
    if (base < MAXN) nbr[base] = (unsigned short)((lane << 6) + b);
    ++base;
  }
  int cnt = *ncnt;            // wave-lockstep: all lanes' LDS writes done
  cnt = cnt < MAXN ? cnt : MAXN;
  unsigned long long acc = 0ull;
  int j = 0;
  for (; j + 4 <= cnt; j += 4) {
    int n0 = nbr[j], n1 = nbr[j + 1], n2 = nbr[j + 2], n3 = nbr[j + 3];
    unsigned long long v0 = SRC[(size_t)n0 * WPR + lane];
    unsigned long long v1 = SRC[(size_t)n1 * WPR + lane];
    unsigned long long v2 = SRC[(size_t)n2 * WPR + lane];
    unsigned long long v3 = SRC[(size_t)n3 * WPR + lane];
    acc |= (v0 | v1) | (v2 | v3);
  }
  for (; j < cnt; ++j) acc |= SRC[(size_t)nbr[j] * WPR + lane];
  return acc;
}

// Masked dot of bitset word against v, complement trick for dense words.
__device__ __forceinline__ float masked_dot(
    unsigned long long m, const float* __restrict__ v,
    const float* __restrict__ wsum, int lane) {
  int cnt = __popcll(m);
  bool inv = cnt > 32;
  unsigned long long it = inv ? ~m : m;
  float part = inv ? wsum[lane] : 0.f;
  float sgn = inv ? -1.f : 1.f;
  const float* p = v + (lane << 6);
  while (it) {
    int b = __builtin_ctzll(it);
    it &= it - 1ull;
    part += sgn * p[b];
  }
  return part;
}

__global__ __launch_bounds__(256) void hop2_kernel(
    const unsigned long long* __restrict__ A, unsigned long long* __restrict__ A2,
    const float* __restrict__ a1, const float* __restrict__ ws1,
    const float* __restrict__ s1, float* __restrict__ s2, float* __restrict__ a2,
    float* __restrict__ ws2) {
  __shared__ unsigned short nbr[4][MAXN];
  __shared__ int ncnt[4];
  int gid = blockIdx.x * 256 + threadIdx.x;
  int i = gid >> 6, wave = threadIdx.x >> 6, lane = gid & 63;
  unsigned long long acc = gather_row_fast(A, A, i, lane, nbr[wave], &ncnt[wave]);
  A2[(size_t)i * WPR + lane] = acc;
  float part = masked_dot(acc, a1, ws1, lane);
  part = wave_sum64(part);
  if (lane == 0) {
    float s2v = fmaf(1.0986122886681098f, part, s1[i]);  // + ln3 * t2
    s2[i] = s2v;
    float a2v = a1[i] + s2v;
    a2[i] = a2v;
    atomicAdd(&ws2[i >> 6], a2v);  // fold ws2 reduction into epilogue
  }
}

__global__ __launch_bounds__(256) void hop3_kernel(
    const unsigned long long* __restrict__ A, const unsigned long long* __restrict__ A2,
    const float* __restrict__ a2, const float* __restrict__ ws2,
    const float* __restrict__ s2, float* __restrict__ out) {
  __shared__ unsigned short nbr[4][MAXN];
  __shared__ int ncnt[4];
  int gid = blockIdx.x * 256 + threadIdx.x;
  int i = gid >> 6, wave = threadIdx.x >> 6, lane = gid & 63;
  unsigned long long acc = gather_row_fast(A, A2, i, lane, nbr[wave], &ncnt[wave]);
  float part = masked_dot(acc, a2, ws2, lane);
  part = wave_sum64(part);
  if (lane == 0) {
    // out = a2 + s3,  s3 = s2 + ln4 * t3
    out[i] = a2[i] + fmaf(1.3862943611198906f, part, s2[i]);
  }
}

extern "C" void kernel_launch(void* const* d_in, const int* in_sizes, int n_in,
                              void* d_out, int out_size, void* d_ws, size_t ws_size,
                              hipStream_t stream) {
  const float* coeffs = (const float*)d_in[0];
  const int*   edge   = (const int*)d_in[1];   // [2, NE] int32
  const float* W0 = (const float*)d_in[2];
  const float* b0 = (const float*)d_in[3];
  const float* W1 = (const float*)d_in[4];
  const float* W2 = (const float*)d_in[5];
  const float* W3 = (const float*)d_in[6];
  const float* b3 = (const float*)d_in[7];
  float* out = (float*)d_out;

  char* ws = (char*)d_ws;
  // Layout (single zeroed region first): [A 2MB | s1 16KB | ws2 256B] then
  // A2 at 4MB, small vectors at 6MB. Total ~6.1 MB of ws used.
  unsigned long long* A  = (unsigned long long*)ws;
  float* s1  = (float*)(ws + (2u << 20));
  float* ws2 = (float*)(ws + (2u << 20) + 16384);
  unsigned long long* A2 = (unsigned long long*)(ws + (4u << 20));
  float* vec = (float*)(ws + (6u << 20));
  float* a0v = vec;              // 4096
  float* a1v = vec + 4096;
  float* s2  = vec + 8192;
  float* a2v = vec + 12288;
  float* ws1 = vec + 16384;      // 64

  // ---- MLP (all layers fused): coeffs -> a0 ----
  mlp_all<<<NN / 8, 256, 0, stream>>>(coeffs, W0, b0, W1, W2, W3, b3, a0v);

  // ---- zero A + s1 + ws2 in ONE memset (ws is poisoned 0xAA each call) ----
  hipMemsetAsync(A, 0, (2u << 20) + 16384 + 256, stream);

  build_graph<<<NE / 256, 256, 0, stream>>>(edge, edge + NE, a0v, A, s1);
  a1_ws<<<1, 256, 0, stream>>>(a0v, s1, a1v, ws1);
  hop2_kernel<<<NN / 4, 256, 0, stream>>>(A, A2, a1v, ws1, s1, s2, a2v, ws2);
  hop3_kernel<<<NN / 4, 256, 0, stream>>>(A, A2, a2v, ws2, s2, out);
}